// Round 13
// baseline (199.691 us; speedup 1.0000x reference)
//
#include <hip/hip_runtime.h>
#include <math.h>

#define C_IN 128
#define C_HID 128
#define C_OUT 64
#define BN_EPS 1e-5f
#define CHUNK 1024
#define NBB 96          // fill2 blocks per bucket
#define CAP 108192      // bucket capacity
#define LSTR 67         // LDS row stride in uints (pairs)

typedef unsigned int uint;
typedef unsigned short ushort;
typedef int iv4 __attribute__((ext_vector_type(4)));
typedef short bfx8 __attribute__((ext_vector_type(8)));
typedef float fx4 __attribute__((ext_vector_type(4)));

__device__ __forceinline__ uint bfr(float f) {
    uint u = __float_as_uint(f);
    return (u + 0x7fffu + ((u >> 16) & 1u)) >> 16;
}
__device__ __forceinline__ uint pk(float a, float b) { return bfr(a) | (bfr(b) << 16); }
__device__ __forceinline__ float bl(uint u) { return __uint_as_float(u << 16); }
__device__ __forceinline__ float bh(uint u) { return __uint_as_float(u & 0xffff0000u); }

// ---------------- zero workspace ----------------
__global__ __launch_bounds__(256) void k_zero(int* __restrict__ deg,
                                              float* __restrict__ gsum,
                                              float* __restrict__ gss,
                                              int* __restrict__ bcur, int n) {
    int i = blockIdx.x * 256 + threadIdx.x;
    if (i < n) deg[i] = 0;
    else if (i < n + 128) gsum[i - n] = 0.f;
    else if (i < n + 256) gss[i - n - 128] = 0.f;
    else if (i < n + 264) bcur[i - n - 256] = 0;
}

// ---------------- phase A: deg histogram + bucket edges by dst range ----------------
__global__ __launch_bounds__(256) void k_bucket(const int* __restrict__ src,
                                                const int* __restrict__ dst,
                                                int* __restrict__ deg,
                                                int* __restrict__ bcur,
                                                int2* __restrict__ stage,
                                                int E, float binv) {
    __shared__ int cnt[8], base[8], off[8];
    if (threadIdx.x < 8) { cnt[threadIdx.x] = 0; off[threadIdx.x] = 0; }
    __syncthreads();
    int e0 = blockIdx.x * CHUNK;
    int e1 = e0 + CHUNK; if (e1 > E) e1 = E;
    int nv = (e1 - e0) & ~3;
    for (int e = e0 + threadIdx.x * 4; e < e0 + nv; e += 1024) {
        iv4 d4 = *(const iv4*)&dst[e];
        #pragma unroll
        for (int j = 0; j < 4; ++j) {
            int d = d4[j];
            atomicAdd(&deg[d], 1);
            int b = (int)((float)d * binv); if (b > 7) b = 7;
            atomicAdd(&cnt[b], 1);
        }
    }
    for (int e = e0 + nv + threadIdx.x; e < e1; e += 256) {
        int d = dst[e];
        atomicAdd(&deg[d], 1);
        int b = (int)((float)d * binv); if (b > 7) b = 7;
        atomicAdd(&cnt[b], 1);
    }
    __syncthreads();
    if (threadIdx.x < 8) base[threadIdx.x] = atomicAdd(&bcur[threadIdx.x], cnt[threadIdx.x]);
    __syncthreads();
    for (int e = e0 + threadIdx.x * 4; e < e0 + nv; e += 1024) {
        iv4 d4 = *(const iv4*)&dst[e];
        iv4 s4 = *(const iv4*)&src[e];
        #pragma unroll
        for (int j = 0; j < 4; ++j) {
            int d = d4[j], s = s4[j];
            int b = (int)((float)d * binv); if (b > 7) b = 7;
            int o = base[b] + atomicAdd(&off[b], 1);
            if (o < CAP) stage[(size_t)b * CAP + o] = make_int2(d, s);
        }
    }
    for (int e = e0 + nv + threadIdx.x; e < e1; e += 256) {
        int d = dst[e], s = src[e];
        int b = (int)((float)d * binv); if (b > 7) b = 7;
        int o = base[b] + atomicAdd(&off[b], 1);
        if (o < CAP) stage[(size_t)b * CAP + o] = make_int2(d, s);
    }
}

// ---------------- scan: per-block partials ----------------
__global__ __launch_bounds__(256) void k_part(const int* __restrict__ deg,
                                              int* __restrict__ part, int n) {
    int i = blockIdx.x * 256 + threadIdx.x;
    int v = (i < n) ? deg[i] : 0;
    #pragma unroll
    for (int o = 32; o > 0; o >>= 1) v += __shfl_down(v, o);
    __shared__ int ls[4];
    if ((threadIdx.x & 63) == 0) ls[threadIdx.x >> 6] = v;
    __syncthreads();
    if (threadIdx.x == 0) part[blockIdx.x] = ls[0] + ls[1] + ls[2] + ls[3];
}

// ---------------- scan: apply (self-computed block offset) ----------------
__global__ __launch_bounds__(256) void k_apply(const int* __restrict__ deg,
                                               const int* __restrict__ part,
                                               int* __restrict__ rowstart,
                                               int* __restrict__ cursor,
                                               float* __restrict__ dinv, int n, int nb) {
    const int tid = threadIdx.x;
    int pv = (tid < blockIdx.x && tid < nb) ? part[tid] : 0;
    #pragma unroll
    for (int o = 32; o > 0; o >>= 1) pv += __shfl_down(pv, o);
    __shared__ int ws[4];
    if ((tid & 63) == 0) ws[tid >> 6] = pv;
    __syncthreads();
    int off = ws[0] + ws[1] + ws[2] + ws[3];

    int i = blockIdx.x * 256 + tid;
    int d = (i < n) ? deg[i] : 0;
    __shared__ int s[256];
    s[tid] = d;
    __syncthreads();
    for (int o = 1; o < 256; o <<= 1) {
        int t = (tid >= o) ? s[tid - o] : 0;
        __syncthreads();
        s[tid] += t;
        __syncthreads();
    }
    int incl = s[tid];
    if (i < n) {
        rowstart[i] = off + incl - d;
        cursor[i]   = off + incl - d;
        dinv[i] = rsqrtf((float)(d + 1));
        if (i == n - 1) rowstart[n] = off + incl;
    }
}

// ---------------- phase B: CSR fill from buckets, XCD-pinned ----------------
__global__ __launch_bounds__(256) void k_fill2(const int2* __restrict__ stage,
                                               const int* __restrict__ bcur,
                                               int* __restrict__ cursor,
                                               int* __restrict__ csr) {
    int b = blockIdx.x & 7;
    int j = blockIdx.x >> 3;
    int cnt = bcur[b]; if (cnt > CAP) cnt = CAP;
    const int2* sp = stage + (size_t)b * CAP;
    for (int i = j * 256 + threadIdx.x; i < cnt; i += NBB * 256) {
        int2 pr = sp[i];
        csr[atomicAdd(&cursor[pr.x], 1)] = pr.y;
    }
}

// ---------------- GEMM1 (MFMA): h = bf16(x) @ bf16(W1) ----------------
__global__ __launch_bounds__(256) void k_gemm1(const float* __restrict__ x,
                                               const float* __restrict__ W,
                                               ushort* __restrict__ h, int n) {
    __shared__ uint xsp[64 * LSTR];
    __shared__ uint wtp[128 * LSTR];
    const int tid = threadIdx.x;
    const int w = tid >> 6, l = tid & 63;
    const int lo = l & 15, hi = l >> 4;
    const int base = blockIdx.x * 64;

    for (int idx = tid; idx < 64 * 32; idx += 256) {
        int row = idx >> 5, c4 = (idx & 31) * 4;
        float4 v = make_float4(0.f, 0.f, 0.f, 0.f);
        if (base + row < n) v = *(const float4*)&x[(size_t)(base + row) * C_IN + c4];
        xsp[row * LSTR + (c4 >> 1)]     = pk(v.x, v.y);
        xsp[row * LSTR + (c4 >> 1) + 1] = pk(v.z, v.w);
    }
    for (int idx = tid; idx < 64 * 32; idx += 256) {
        int kk = idx >> 5, n4 = (idx & 31) * 4;
        float4 w0 = *(const float4*)&W[(size_t)(2 * kk) * C_HID + n4];
        float4 w1 = *(const float4*)&W[(size_t)(2 * kk + 1) * C_HID + n4];
        wtp[(n4 + 0) * LSTR + kk] = pk(w0.x, w1.x);
        wtp[(n4 + 1) * LSTR + kk] = pk(w0.y, w1.y);
        wtp[(n4 + 2) * LSTR + kk] = pk(w0.z, w1.z);
        wtp[(n4 + 3) * LSTR + kk] = pk(w0.w, w1.w);
    }
    __syncthreads();

    fx4 acc[8];
    #pragma unroll
    for (int t = 0; t < 8; ++t) acc[t] = (fx4)(0.f);

    const int arow = (w * 16 + lo) * LSTR;
    #pragma unroll
    for (int kb = 0; kb < 4; ++kb) {
        const int ka = kb * 16 + hi * 4;
        uint4 ua;
        ua.x = xsp[arow + ka]; ua.y = xsp[arow + ka + 1];
        ua.z = xsp[arow + ka + 2]; ua.w = xsp[arow + ka + 3];
        bfx8 af = __builtin_bit_cast(bfx8, ua);
        #pragma unroll
        for (int nt = 0; nt < 8; ++nt) {
            const int brow = (nt * 16 + lo) * LSTR;
            uint4 ub;
            ub.x = wtp[brow + ka]; ub.y = wtp[brow + ka + 1];
            ub.z = wtp[brow + ka + 2]; ub.w = wtp[brow + ka + 3];
            bfx8 bf_ = __builtin_bit_cast(bfx8, ub);
            acc[nt] = __builtin_amdgcn_mfma_f32_16x16x32_bf16(af, bf_, acc[nt], 0, 0, 0);
        }
    }
    #pragma unroll
    for (int nt = 0; nt < 8; ++nt) {
        #pragma unroll
        for (int r = 0; r < 4; ++r) {
            int row = base + w * 16 + hi * 4 + r;
            if (row < n) h[(size_t)row * C_HID + nt * 16 + lo] = (ushort)bfr(acc[nt][r]);
        }
    }
}

// ---------------- gather1: bf16 rows, 1 node per 16 lanes, unroll 8 ----------------
__global__ __launch_bounds__(256) void k_gather1(const uint4* __restrict__ h,
                                                 const float* __restrict__ dinv,
                                                 const int* __restrict__ rowstart,
                                                 const int* __restrict__ csr,
                                                 const float* __restrict__ b,
                                                 uint4* __restrict__ g1, int n) {
    int v = (blockIdx.x * 256 + threadIdx.x) >> 4;
    int l = threadIdx.x & 15;
    if (v >= n) return;
    float dv = dinv[v];
    int s0 = rowstart[v], s1 = rowstart[v + 1];
    float4 aA, aB;
    {
        uint4 u = h[(size_t)v * 16 + l];
        aA.x = dv * bl(u.x); aA.y = dv * bh(u.x); aA.z = dv * bl(u.y); aA.w = dv * bh(u.y);
        aB.x = dv * bl(u.z); aB.y = dv * bh(u.z); aB.z = dv * bl(u.w); aB.w = dv * bh(u.w);
    }
    int e = s0;
    for (; e + 7 < s1; e += 8) {
        int i0 = csr[e],     i1 = csr[e + 1], i2 = csr[e + 2], i3 = csr[e + 3];
        int i4 = csr[e + 4], i5 = csr[e + 5], i6 = csr[e + 6], i7 = csr[e + 7];
        float w0 = dinv[i0], w1 = dinv[i1], w2 = dinv[i2], w3 = dinv[i3];
        float w4 = dinv[i4], w5 = dinv[i5], w6 = dinv[i6], w7 = dinv[i7];
        uint4 u0 = h[(size_t)i0 * 16 + l], u1 = h[(size_t)i1 * 16 + l];
        uint4 u2 = h[(size_t)i2 * 16 + l], u3 = h[(size_t)i3 * 16 + l];
        uint4 u4 = h[(size_t)i4 * 16 + l], u5 = h[(size_t)i5 * 16 + l];
        uint4 u6 = h[(size_t)i6 * 16 + l], u7 = h[(size_t)i7 * 16 + l];
        aA.x += w0*bl(u0.x) + w1*bl(u1.x) + w2*bl(u2.x) + w3*bl(u3.x)
              + w4*bl(u4.x) + w5*bl(u5.x) + w6*bl(u6.x) + w7*bl(u7.x);
        aA.y += w0*bh(u0.x) + w1*bh(u1.x) + w2*bh(u2.x) + w3*bh(u3.x)
              + w4*bh(u4.x) + w5*bh(u5.x) + w6*bh(u6.x) + w7*bh(u7.x);
        aA.z += w0*bl(u0.y) + w1*bl(u1.y) + w2*bl(u2.y) + w3*bl(u3.y)
              + w4*bl(u4.y) + w5*bl(u5.y) + w6*bl(u6.y) + w7*bl(u7.y);
        aA.w += w0*bh(u0.y) + w1*bh(u1.y) + w2*bh(u2.y) + w3*bh(u3.y)
              + w4*bh(u4.y) + w5*bh(u5.y) + w6*bh(u6.y) + w7*bh(u7.y);
        aB.x += w0*bl(u0.z) + w1*bl(u1.z) + w2*bl(u2.z) + w3*bl(u3.z)
              + w4*bl(u4.z) + w5*bl(u5.z) + w6*bl(u6.z) + w7*bl(u7.z);
        aB.y += w0*bh(u0.z) + w1*bh(u1.z) + w2*bh(u2.z) + w3*bh(u3.z)
              + w4*bh(u4.z) + w5*bh(u5.z) + w6*bh(u6.z) + w7*bh(u7.z);
        aB.z += w0*bl(u0.w) + w1*bl(u1.w) + w2*bl(u2.w) + w3*bl(u3.w)
              + w4*bl(u4.w) + w5*bl(u5.w) + w6*bl(u6.w) + w7*bl(u7.w);
        aB.w += w0*bh(u0.w) + w1*bh(u1.w) + w2*bh(u2.w) + w3*bh(u3.w)
              + w4*bh(u4.w) + w5*bh(u5.w) + w6*bh(u6.w) + w7*bh(u7.w);
    }
    for (; e < s1; ++e) {
        int s = csr[e];
        float w = dinv[s];
        uint4 u = h[(size_t)s * 16 + l];
        aA.x += w * bl(u.x); aA.y += w * bh(u.x); aA.z += w * bl(u.y); aA.w += w * bh(u.y);
        aB.x += w * bl(u.z); aB.y += w * bh(u.z); aB.z += w * bl(u.w); aB.w += w * bh(u.w);
    }
    float4 b0 = *(const float4*)&b[l * 8];
    float4 b1v = *(const float4*)&b[l * 8 + 4];
    uint4 o;
    o.x = pk(aA.x * dv + b0.x,  aA.y * dv + b0.y);
    o.y = pk(aA.z * dv + b0.z,  aA.w * dv + b0.w);
    o.z = pk(aB.x * dv + b1v.x, aB.y * dv + b1v.y);
    o.w = pk(aB.z * dv + b1v.z, aB.w * dv + b1v.w);
    g1[(size_t)v * 16 + l] = o;
}

// ---------------- BN stats from bf16 g1 ----------------
__global__ __launch_bounds__(256) void k_bnstats(const uint4* __restrict__ g,
                                                 float* __restrict__ gsum,
                                                 float* __restrict__ gss, int n) {
    float4 sA = make_float4(0.f,0.f,0.f,0.f), sB = sA, qA = sA, qB = sA;
    int total = n * 16;
    int stride = gridDim.x * 256;
    for (int i = blockIdx.x * 256 + threadIdx.x; i < total; i += stride) {
        uint4 u = g[i];
        float v0 = bl(u.x), v1 = bh(u.x), v2 = bl(u.y), v3 = bh(u.y);
        float v4 = bl(u.z), v5 = bh(u.z), v6 = bl(u.w), v7 = bh(u.w);
        sA.x += v0; sA.y += v1; sA.z += v2; sA.w += v3;
        sB.x += v4; sB.y += v5; sB.z += v6; sB.w += v7;
        qA.x += v0*v0; qA.y += v1*v1; qA.z += v2*v2; qA.w += v3*v3;
        qB.x += v4*v4; qB.y += v5*v5; qB.z += v6*v6; qB.w += v7*v7;
    }
    __shared__ float sb[128], qb[128];
    if (threadIdx.x < 128) { sb[threadIdx.x] = 0.f; qb[threadIdx.x] = 0.f; }
    __syncthreads();
    int c0 = (threadIdx.x & 15) * 8;
    atomicAdd(&sb[c0+0], sA.x); atomicAdd(&sb[c0+1], sA.y); atomicAdd(&sb[c0+2], sA.z); atomicAdd(&sb[c0+3], sA.w);
    atomicAdd(&sb[c0+4], sB.x); atomicAdd(&sb[c0+5], sB.y); atomicAdd(&sb[c0+6], sB.z); atomicAdd(&sb[c0+7], sB.w);
    atomicAdd(&qb[c0+0], qA.x); atomicAdd(&qb[c0+1], qA.y); atomicAdd(&qb[c0+2], qA.z); atomicAdd(&qb[c0+3], qA.w);
    atomicAdd(&qb[c0+4], qB.x); atomicAdd(&qb[c0+5], qB.y); atomicAdd(&qb[c0+6], qB.z); atomicAdd(&qb[c0+7], qB.w);
    __syncthreads();
    if (threadIdx.x < 128) {
        atomicAdd(&gsum[threadIdx.x], sb[threadIdx.x]);
        atomicAdd(&gss[threadIdx.x], qb[threadIdx.x]);
    }
}

// ---------------- GEMM2 (MFMA): h2 = bf16(elu(bn(g1))) @ bf16(W2) ----------------
__global__ __launch_bounds__(256) void k_gemm2(const uint4* __restrict__ g1,
                                               const float* __restrict__ W2,
                                               const float* __restrict__ gsum,
                                               const float* __restrict__ gss,
                                               const float* __restrict__ gamma,
                                               const float* __restrict__ beta,
                                               ushort* __restrict__ h2, int n) {
    __shared__ uint xsp[64 * LSTR];
    __shared__ uint wtp[64 * LSTR];
    __shared__ float sc[C_HID], sh[C_HID];
    const int tid = threadIdx.x;
    const int w = tid >> 6, l = tid & 63;
    const int lo = l & 15, hi = l >> 4;
    const int base = blockIdx.x * 64;

    if (tid < C_HID) {
        float inv_n = 1.f / (float)n;
        float mean = gsum[tid] * inv_n;
        float var = gss[tid] * inv_n - mean * mean;
        float s = gamma[tid] * rsqrtf(var + BN_EPS);
        sc[tid] = s;
        sh[tid] = beta[tid] - mean * s;
    }
    __syncthreads();

    for (int idx = tid; idx < 64 * 16; idx += 256) {
        int row = idx >> 4, q = idx & 15;
        int k8 = q * 8;
        uint4 u = make_uint4(0, 0, 0, 0);
        if (base + row < n) u = g1[(size_t)(base + row) * 16 + q];
        float t;
        float e0, e1, e2, e3, e4, e5, e6, e7;
        t = bl(u.x) * sc[k8+0] + sh[k8+0]; e0 = t > 0.f ? t : expm1f(t);
        t = bh(u.x) * sc[k8+1] + sh[k8+1]; e1 = t > 0.f ? t : expm1f(t);
        t = bl(u.y) * sc[k8+2] + sh[k8+2]; e2 = t > 0.f ? t : expm1f(t);
        t = bh(u.y) * sc[k8+3] + sh[k8+3]; e3 = t > 0.f ? t : expm1f(t);
        t = bl(u.z) * sc[k8+4] + sh[k8+4]; e4 = t > 0.f ? t : expm1f(t);
        t = bh(u.z) * sc[k8+5] + sh[k8+5]; e5 = t > 0.f ? t : expm1f(t);
        t = bl(u.w) * sc[k8+6] + sh[k8+6]; e6 = t > 0.f ? t : expm1f(t);
        t = bh(u.w) * sc[k8+7] + sh[k8+7]; e7 = t > 0.f ? t : expm1f(t);
        int wbase = row * LSTR + q * 4;
        xsp[wbase + 0] = pk(e0, e1);
        xsp[wbase + 1] = pk(e2, e3);
        xsp[wbase + 2] = pk(e4, e5);
        xsp[wbase + 3] = pk(e6, e7);
    }
    for (int idx = tid; idx < 64 * 16; idx += 256) {
        int kk = idx >> 4, n4 = (idx & 15) * 4;
        float4 w0 = *(const float4*)&W2[(size_t)(2 * kk) * C_OUT + n4];
        float4 w1 = *(const float4*)&W2[(size_t)(2 * kk + 1) * C_OUT + n4];
        wtp[(n4 + 0) * LSTR + kk] = pk(w0.x, w1.x);
        wtp[(n4 + 1) * LSTR + kk] = pk(w0.y, w1.y);
        wtp[(n4 + 2) * LSTR + kk] = pk(w0.z, w1.z);
        wtp[(n4 + 3) * LSTR + kk] = pk(w0.w, w1.w);
    }
    __syncthreads();

    fx4 acc[4];
    #pragma unroll
    for (int t = 0; t < 4; ++t) acc[t] = (fx4)(0.f);

    const int arow = (w * 16 + lo) * LSTR;
    #pragma unroll
    for (int kb = 0; kb < 4; ++kb) {
        const int ka = kb * 16 + hi * 4;
        uint4 ua;
        ua.x = xsp[arow + ka]; ua.y = xsp[arow + ka + 1];
        ua.z = xsp[arow + ka + 2]; ua.w = xsp[arow + ka + 3];
        bfx8 af = __builtin_bit_cast(bfx8, ua);
        #pragma unroll
        for (int nt = 0; nt < 4; ++nt) {
            const int brow = (nt * 16 + lo) * LSTR;
            uint4 ub;
            ub.x = wtp[brow + ka]; ub.y = wtp[brow + ka + 1];
            ub.z = wtp[brow + ka + 2]; ub.w = wtp[brow + ka + 3];
            bfx8 bf_ = __builtin_bit_cast(bfx8, ub);
            acc[nt] = __builtin_amdgcn_mfma_f32_16x16x32_bf16(af, bf_, acc[nt], 0, 0, 0);
        }
    }
    #pragma unroll
    for (int nt = 0; nt < 4; ++nt) {
        #pragma unroll
        for (int r = 0; r < 4; ++r) {
            int row = base + w * 16 + hi * 4 + r;
            if (row < n) h2[(size_t)row * C_OUT + nt * 16 + lo] = (ushort)bfr(acc[nt][r]);
        }
    }
}

// ---------------- gather2: bf16 rows, 1 node per 16 lanes, unroll 8 ----------------
__global__ __launch_bounds__(256) void k_gather2(const uint2* __restrict__ h,
                                                 const float* __restrict__ dinv,
                                                 const int* __restrict__ rowstart,
                                                 const int* __restrict__ csr,
                                                 const float* __restrict__ b,
                                                 float* __restrict__ out, int n) {
    int v = (blockIdx.x * 256 + threadIdx.x) >> 4;
    int l = threadIdx.x & 15;
    if (v >= n) return;
    float dv = dinv[v];
    int s0 = rowstart[v], s1 = rowstart[v + 1];
    float4 a;
    {
        uint2 u = h[(size_t)v * 16 + l];
        a.x = dv * bl(u.x); a.y = dv * bh(u.x); a.z = dv * bl(u.y); a.w = dv * bh(u.y);
    }
    int e = s0;
    for (; e + 7 < s1; e += 8) {
        int i0 = csr[e],     i1 = csr[e + 1], i2 = csr[e + 2], i3 = csr[e + 3];
        int i4 = csr[e + 4], i5 = csr[e + 5], i6 = csr[e + 6], i7 = csr[e + 7];
        float w0 = dinv[i0], w1 = dinv[i1], w2 = dinv[i2], w3 = dinv[i3];
        float w4 = dinv[i4], w5 = dinv[i5], w6 = dinv[i6], w7 = dinv[i7];
        uint2 u0 = h[(size_t)i0 * 16 + l], u1 = h[(size_t)i1 * 16 + l];
        uint2 u2 = h[(size_t)i2 * 16 + l], u3 = h[(size_t)i3 * 16 + l];
        uint2 u4 = h[(size_t)i4 * 16 + l], u5 = h[(size_t)i5 * 16 + l];
        uint2 u6 = h[(size_t)i6 * 16 + l], u7 = h[(size_t)i7 * 16 + l];
        a.x += w0*bl(u0.x) + w1*bl(u1.x) + w2*bl(u2.x) + w3*bl(u3.x)
             + w4*bl(u4.x) + w5*bl(u5.x) + w6*bl(u6.x) + w7*bl(u7.x);
        a.y += w0*bh(u0.x) + w1*bh(u1.x) + w2*bh(u2.x) + w3*bh(u3.x)
             + w4*bh(u4.x) + w5*bh(u5.x) + w6*bh(u6.x) + w7*bh(u7.x);
        a.z += w0*bl(u0.y) + w1*bl(u1.y) + w2*bl(u2.y) + w3*bl(u3.y)
             + w4*bl(u4.y) + w5*bl(u5.y) + w6*bl(u6.y) + w7*bl(u7.y);
        a.w += w0*bh(u0.y) + w1*bh(u1.y) + w2*bh(u2.y) + w3*bh(u3.y)
             + w4*bh(u4.y) + w5*bh(u5.y) + w6*bh(u6.y) + w7*bh(u7.y);
    }
    for (; e < s1; ++e) {
        int s = csr[e];
        float w = dinv[s];
        uint2 u = h[(size_t)s * 16 + l];
        a.x += w * bl(u.x); a.y += w * bh(u.x); a.z += w * bl(u.y); a.w += w * bh(u.y);
    }
    float4 bb = *(const float4*)&b[l * 4];
    float4 o;
    o.x = a.x * dv + bb.x; o.y = a.y * dv + bb.y;
    o.z = a.z * dv + bb.z; o.w = a.w * dv + bb.w;
    *(float4*)&out[(size_t)v * C_OUT + l * 4] = o;
}

// ---------------- launch ----------------
extern "C" void kernel_launch(void* const* d_in, const int* in_sizes, int n_in,
                              void* d_out, int out_size, void* d_ws, size_t ws_size,
                              hipStream_t stream) {
    const float* x     = (const float*)d_in[0];
    const int*   ei    = (const int*)d_in[1];
    const float* W1    = (const float*)d_in[2];
    const float* b1    = (const float*)d_in[3];
    const float* gamma = (const float*)d_in[4];
    const float* beta  = (const float*)d_in[5];
    const float* W2    = (const float*)d_in[6];
    const float* b2    = (const float*)d_in[7];
    float* out = (float*)d_out;

    const int n = in_sizes[0] / C_IN;     // 50000
    const int E = in_sizes[1] / 2;        // 800000
    const int* src = ei;
    const int* dst = ei + E;

    char* p = (char*)d_ws;
    auto carve = [&](size_t bytes) {
        char* r = p;
        p += (bytes + 255) & ~(size_t)255;
        return r;
    };
    int*    deg      = (int*)   carve((size_t)n * 4);
    int*    rowstart = (int*)   carve((size_t)(n + 1) * 4);
    int*    cursor   = (int*)   carve((size_t)n * 4);
    int*    csr      = (int*)   carve((size_t)E * 4);
    float*  dinv     = (float*) carve((size_t)n * 4);
    ushort* h1       = (ushort*)carve((size_t)n * 128 * 2);
    ushort* g1       = (ushort*)carve((size_t)n * 128 * 2);
    ushort* h2       = (ushort*)carve((size_t)n * 64 * 2);
    float*  gsum     = (float*) carve(C_HID * 4);
    float*  gss      = (float*) carve(C_HID * 4);
    int*    part     = (int*)   carve(256 * 4);
    int*    bcur     = (int*)   carve(8 * 4);
    int2*   stage    = (int2*)  carve((size_t)8 * CAP * 8);

    const int nb = (n + 255) / 256;            // 196
    const int gblocks = (n * 16 + 255) / 256;  // 1 node per 16 lanes
    const int fc = (E + CHUNK - 1) / CHUNK;    // 782
    const float binv = 8.0f / (float)n;

    k_zero<<<(n + 264 + 255) / 256, 256, 0, stream>>>(deg, gsum, gss, bcur, n);
    k_bucket<<<fc, 256, 0, stream>>>(src, dst, deg, bcur, stage, E, binv);
    k_gemm1<<<(n + 63) / 64, 256, 0, stream>>>(x, W1, h1, n);
    k_part<<<nb, 256, 0, stream>>>(deg, part, n);
    k_apply<<<nb, 256, 0, stream>>>(deg, part, rowstart, cursor, dinv, n, nb);
    k_fill2<<<8 * NBB, 256, 0, stream>>>(stage, bcur, cursor, csr);
    k_gather1<<<gblocks, 256, 0, stream>>>((const uint4*)h1, dinv, rowstart, csr, b1, (uint4*)g1, n);
    k_bnstats<<<512, 256, 0, stream>>>((const uint4*)g1, gsum, gss, n);
    k_gemm2<<<(n + 63) / 64, 256, 0, stream>>>((const uint4*)g1, W2, gsum, gss, gamma, beta, h2, n);
    k_gather2<<<gblocks, 256, 0, stream>>>((const uint2*)h2, dinv, rowstart, csr, b2, out, n);
}

// Round 14
// 190.686 us; speedup vs baseline: 1.0472x; 1.0472x over previous
//
#include <hip/hip_runtime.h>
#include <math.h>

#define C_IN 128
#define C_HID 128
#define C_OUT 64
#define BN_EPS 1e-5f
#define CHUNK 1024
#define NBB 96          // fill2 blocks per bucket
#define CAP 108192      // bucket capacity
#define LSTR 67         // LDS row stride in uints (pairs)

typedef unsigned int uint;
typedef unsigned short ushort;
typedef int iv4 __attribute__((ext_vector_type(4)));
typedef short bfx8 __attribute__((ext_vector_type(8)));
typedef float fx4 __attribute__((ext_vector_type(4)));

__device__ __forceinline__ uint bfr(float f) {
    uint u = __float_as_uint(f);
    return (u + 0x7fffu + ((u >> 16) & 1u)) >> 16;
}
__device__ __forceinline__ uint pk(float a, float b) { return bfr(a) | (bfr(b) << 16); }
__device__ __forceinline__ float bl(uint u) { return __uint_as_float(u << 16); }
__device__ __forceinline__ float bh(uint u) { return __uint_as_float(u & 0xffff0000u); }

// ---------------- zero workspace ----------------
__global__ __launch_bounds__(256) void k_zero(int* __restrict__ deg,
                                              float* __restrict__ gsum,
                                              float* __restrict__ gss,
                                              int* __restrict__ bcur, int n) {
    int i = blockIdx.x * 256 + threadIdx.x;
    if (i < n) deg[i] = 0;
    else if (i < n + 128) gsum[i - n] = 0.f;
    else if (i < n + 256) gss[i - n - 128] = 0.f;
    else if (i < n + 264) bcur[i - n - 256] = 0;
}

// ---------------- phase A: deg histogram + bucket edges by dst range ----------------
__global__ __launch_bounds__(256) void k_bucket(const int* __restrict__ src,
                                                const int* __restrict__ dst,
                                                int* __restrict__ deg,
                                                int* __restrict__ bcur,
                                                int2* __restrict__ stage,
                                                int E, float binv) {
    __shared__ int cnt[8], base[8], off[8];
    if (threadIdx.x < 8) { cnt[threadIdx.x] = 0; off[threadIdx.x] = 0; }
    __syncthreads();
    int e0 = blockIdx.x * CHUNK;
    int e1 = e0 + CHUNK; if (e1 > E) e1 = E;
    int nv = (e1 - e0) & ~3;
    for (int e = e0 + threadIdx.x * 4; e < e0 + nv; e += 1024) {
        iv4 d4 = *(const iv4*)&dst[e];
        #pragma unroll
        for (int j = 0; j < 4; ++j) {
            int d = d4[j];
            atomicAdd(&deg[d], 1);
            int b = (int)((float)d * binv); if (b > 7) b = 7;
            atomicAdd(&cnt[b], 1);
        }
    }
    for (int e = e0 + nv + threadIdx.x; e < e1; e += 256) {
        int d = dst[e];
        atomicAdd(&deg[d], 1);
        int b = (int)((float)d * binv); if (b > 7) b = 7;
        atomicAdd(&cnt[b], 1);
    }
    __syncthreads();
    if (threadIdx.x < 8) base[threadIdx.x] = atomicAdd(&bcur[threadIdx.x], cnt[threadIdx.x]);
    __syncthreads();
    for (int e = e0 + threadIdx.x * 4; e < e0 + nv; e += 1024) {
        iv4 d4 = *(const iv4*)&dst[e];
        iv4 s4 = *(const iv4*)&src[e];
        #pragma unroll
        for (int j = 0; j < 4; ++j) {
            int d = d4[j], s = s4[j];
            int b = (int)((float)d * binv); if (b > 7) b = 7;
            int o = base[b] + atomicAdd(&off[b], 1);
            if (o < CAP) stage[(size_t)b * CAP + o] = make_int2(d, s);
        }
    }
    for (int e = e0 + nv + threadIdx.x; e < e1; e += 256) {
        int d = dst[e], s = src[e];
        int b = (int)((float)d * binv); if (b > 7) b = 7;
        int o = base[b] + atomicAdd(&off[b], 1);
        if (o < CAP) stage[(size_t)b * CAP + o] = make_int2(d, s);
    }
}

// ---------------- scan: per-block partials ----------------
__global__ __launch_bounds__(256) void k_part(const int* __restrict__ deg,
                                              int* __restrict__ part, int n) {
    int i = blockIdx.x * 256 + threadIdx.x;
    int v = (i < n) ? deg[i] : 0;
    #pragma unroll
    for (int o = 32; o > 0; o >>= 1) v += __shfl_down(v, o);
    __shared__ int ls[4];
    if ((threadIdx.x & 63) == 0) ls[threadIdx.x >> 6] = v;
    __syncthreads();
    if (threadIdx.x == 0) part[blockIdx.x] = ls[0] + ls[1] + ls[2] + ls[3];
}

// ---------------- scan: apply (self-computed block offset) ----------------
__global__ __launch_bounds__(256) void k_apply(const int* __restrict__ deg,
                                               const int* __restrict__ part,
                                               int* __restrict__ rowstart,
                                               int* __restrict__ cursor,
                                               float* __restrict__ dinv, int n, int nb) {
    const int tid = threadIdx.x;
    int pv = (tid < blockIdx.x && tid < nb) ? part[tid] : 0;
    #pragma unroll
    for (int o = 32; o > 0; o >>= 1) pv += __shfl_down(pv, o);
    __shared__ int ws[4];
    if ((tid & 63) == 0) ws[tid >> 6] = pv;
    __syncthreads();
    int off = ws[0] + ws[1] + ws[2] + ws[3];

    int i = blockIdx.x * 256 + tid;
    int d = (i < n) ? deg[i] : 0;
    __shared__ int s[256];
    s[tid] = d;
    __syncthreads();
    for (int o = 1; o < 256; o <<= 1) {
        int t = (tid >= o) ? s[tid - o] : 0;
        __syncthreads();
        s[tid] += t;
        __syncthreads();
    }
    int incl = s[tid];
    if (i < n) {
        rowstart[i] = off + incl - d;
        cursor[i]   = off + incl - d;
        dinv[i] = rsqrtf((float)(d + 1));
        if (i == n - 1) rowstart[n] = off + incl;
    }
}

// ---------------- phase B: CSR fill from buckets, XCD-pinned ----------------
__global__ __launch_bounds__(256) void k_fill2(const int2* __restrict__ stage,
                                               const int* __restrict__ bcur,
                                               int* __restrict__ cursor,
                                               int* __restrict__ csr) {
    int b = blockIdx.x & 7;
    int j = blockIdx.x >> 3;
    int cnt = bcur[b]; if (cnt > CAP) cnt = CAP;
    const int2* sp = stage + (size_t)b * CAP;
    for (int i = j * 256 + threadIdx.x; i < cnt; i += NBB * 256) {
        int2 pr = sp[i];
        csr[atomicAdd(&cursor[pr.x], 1)] = pr.y;
    }
}

// ---------------- GEMM1 (MFMA): h = bf16(x) @ bf16(W1) ----------------
__global__ __launch_bounds__(256) void k_gemm1(const float* __restrict__ x,
                                               const float* __restrict__ W,
                                               ushort* __restrict__ h, int n) {
    __shared__ uint xsp[64 * LSTR];
    __shared__ uint wtp[128 * LSTR];
    const int tid = threadIdx.x;
    const int w = tid >> 6, l = tid & 63;
    const int lo = l & 15, hi = l >> 4;
    const int base = blockIdx.x * 64;

    for (int idx = tid; idx < 64 * 32; idx += 256) {
        int row = idx >> 5, c4 = (idx & 31) * 4;
        float4 v = make_float4(0.f, 0.f, 0.f, 0.f);
        if (base + row < n) v = *(const float4*)&x[(size_t)(base + row) * C_IN + c4];
        xsp[row * LSTR + (c4 >> 1)]     = pk(v.x, v.y);
        xsp[row * LSTR + (c4 >> 1) + 1] = pk(v.z, v.w);
    }
    for (int idx = tid; idx < 64 * 32; idx += 256) {
        int kk = idx >> 5, n4 = (idx & 31) * 4;
        float4 w0 = *(const float4*)&W[(size_t)(2 * kk) * C_HID + n4];
        float4 w1 = *(const float4*)&W[(size_t)(2 * kk + 1) * C_HID + n4];
        wtp[(n4 + 0) * LSTR + kk] = pk(w0.x, w1.x);
        wtp[(n4 + 1) * LSTR + kk] = pk(w0.y, w1.y);
        wtp[(n4 + 2) * LSTR + kk] = pk(w0.z, w1.z);
        wtp[(n4 + 3) * LSTR + kk] = pk(w0.w, w1.w);
    }
    __syncthreads();

    fx4 acc[8];
    #pragma unroll
    for (int t = 0; t < 8; ++t) acc[t] = (fx4)(0.f);

    const int arow = (w * 16 + lo) * LSTR;
    #pragma unroll
    for (int kb = 0; kb < 4; ++kb) {
        const int ka = kb * 16 + hi * 4;
        uint4 ua;
        ua.x = xsp[arow + ka]; ua.y = xsp[arow + ka + 1];
        ua.z = xsp[arow + ka + 2]; ua.w = xsp[arow + ka + 3];
        bfx8 af = __builtin_bit_cast(bfx8, ua);
        #pragma unroll
        for (int nt = 0; nt < 8; ++nt) {
            const int brow = (nt * 16 + lo) * LSTR;
            uint4 ub;
            ub.x = wtp[brow + ka]; ub.y = wtp[brow + ka + 1];
            ub.z = wtp[brow + ka + 2]; ub.w = wtp[brow + ka + 3];
            bfx8 bf_ = __builtin_bit_cast(bfx8, ub);
            acc[nt] = __builtin_amdgcn_mfma_f32_16x16x32_bf16(af, bf_, acc[nt], 0, 0, 0);
        }
    }
    #pragma unroll
    for (int nt = 0; nt < 8; ++nt) {
        #pragma unroll
        for (int r = 0; r < 4; ++r) {
            int row = base + w * 16 + hi * 4 + r;
            if (row < n) h[(size_t)row * C_HID + nt * 16 + lo] = (ushort)bfr(acc[nt][r]);
        }
    }
}

// ---------------- gather1: bf16 rows, 1 node per 16 lanes, unroll 4 ----------------
__global__ __launch_bounds__(256) void k_gather1(const uint4* __restrict__ h,
                                                 const float* __restrict__ dinv,
                                                 const int* __restrict__ rowstart,
                                                 const int* __restrict__ csr,
                                                 const float* __restrict__ b,
                                                 uint4* __restrict__ g1, int n) {
    int v = (blockIdx.x * 256 + threadIdx.x) >> 4;
    int l = threadIdx.x & 15;
    if (v >= n) return;
    float dv = dinv[v];
    int s0 = rowstart[v], s1 = rowstart[v + 1];
    float4 aA, aB;
    {
        uint4 u = h[(size_t)v * 16 + l];
        aA.x = dv * bl(u.x); aA.y = dv * bh(u.x); aA.z = dv * bl(u.y); aA.w = dv * bh(u.y);
        aB.x = dv * bl(u.z); aB.y = dv * bh(u.z); aB.z = dv * bl(u.w); aB.w = dv * bh(u.w);
    }
    int e = s0;
    for (; e + 3 < s1; e += 4) {
        int i0 = csr[e], i1 = csr[e + 1], i2 = csr[e + 2], i3 = csr[e + 3];
        float w0 = dinv[i0], w1 = dinv[i1], w2 = dinv[i2], w3 = dinv[i3];
        uint4 u0 = h[(size_t)i0 * 16 + l];
        uint4 u1 = h[(size_t)i1 * 16 + l];
        uint4 u2 = h[(size_t)i2 * 16 + l];
        uint4 u3 = h[(size_t)i3 * 16 + l];
        aA.x += w0 * bl(u0.x) + w1 * bl(u1.x) + w2 * bl(u2.x) + w3 * bl(u3.x);
        aA.y += w0 * bh(u0.x) + w1 * bh(u1.x) + w2 * bh(u2.x) + w3 * bh(u3.x);
        aA.z += w0 * bl(u0.y) + w1 * bl(u1.y) + w2 * bl(u2.y) + w3 * bl(u3.y);
        aA.w += w0 * bh(u0.y) + w1 * bh(u1.y) + w2 * bh(u2.y) + w3 * bh(u3.y);
        aB.x += w0 * bl(u0.z) + w1 * bl(u1.z) + w2 * bl(u2.z) + w3 * bl(u3.z);
        aB.y += w0 * bh(u0.z) + w1 * bh(u1.z) + w2 * bh(u2.z) + w3 * bh(u3.z);
        aB.z += w0 * bl(u0.w) + w1 * bl(u1.w) + w2 * bl(u2.w) + w3 * bl(u3.w);
        aB.w += w0 * bh(u0.w) + w1 * bh(u1.w) + w2 * bh(u2.w) + w3 * bh(u3.w);
    }
    for (; e < s1; ++e) {
        int s = csr[e];
        float w = dinv[s];
        uint4 u = h[(size_t)s * 16 + l];
        aA.x += w * bl(u.x); aA.y += w * bh(u.x); aA.z += w * bl(u.y); aA.w += w * bh(u.y);
        aB.x += w * bl(u.z); aB.y += w * bh(u.z); aB.z += w * bl(u.w); aB.w += w * bh(u.w);
    }
    float4 b0 = *(const float4*)&b[l * 8];
    float4 b1v = *(const float4*)&b[l * 8 + 4];
    uint4 o;
    o.x = pk(aA.x * dv + b0.x,  aA.y * dv + b0.y);
    o.y = pk(aA.z * dv + b0.z,  aA.w * dv + b0.w);
    o.z = pk(aB.x * dv + b1v.x, aB.y * dv + b1v.y);
    o.w = pk(aB.z * dv + b1v.z, aB.w * dv + b1v.w);
    g1[(size_t)v * 16 + l] = o;
}

// ---------------- BN stats from bf16 g1 ----------------
__global__ __launch_bounds__(256) void k_bnstats(const uint4* __restrict__ g,
                                                 float* __restrict__ gsum,
                                                 float* __restrict__ gss, int n) {
    float4 sA = make_float4(0.f,0.f,0.f,0.f), sB = sA, qA = sA, qB = sA;
    int total = n * 16;
    int stride = gridDim.x * 256;
    for (int i = blockIdx.x * 256 + threadIdx.x; i < total; i += stride) {
        uint4 u = g[i];
        float v0 = bl(u.x), v1 = bh(u.x), v2 = bl(u.y), v3 = bh(u.y);
        float v4 = bl(u.z), v5 = bh(u.z), v6 = bl(u.w), v7 = bh(u.w);
        sA.x += v0; sA.y += v1; sA.z += v2; sA.w += v3;
        sB.x += v4; sB.y += v5; sB.z += v6; sB.w += v7;
        qA.x += v0*v0; qA.y += v1*v1; qA.z += v2*v2; qA.w += v3*v3;
        qB.x += v4*v4; qB.y += v5*v5; qB.z += v6*v6; qB.w += v7*v7;
    }
    __shared__ float sb[128], qb[128];
    if (threadIdx.x < 128) { sb[threadIdx.x] = 0.f; qb[threadIdx.x] = 0.f; }
    __syncthreads();
    int c0 = (threadIdx.x & 15) * 8;
    atomicAdd(&sb[c0+0], sA.x); atomicAdd(&sb[c0+1], sA.y); atomicAdd(&sb[c0+2], sA.z); atomicAdd(&sb[c0+3], sA.w);
    atomicAdd(&sb[c0+4], sB.x); atomicAdd(&sb[c0+5], sB.y); atomicAdd(&sb[c0+6], sB.z); atomicAdd(&sb[c0+7], sB.w);
    atomicAdd(&qb[c0+0], qA.x); atomicAdd(&qb[c0+1], qA.y); atomicAdd(&qb[c0+2], qA.z); atomicAdd(&qb[c0+3], qA.w);
    atomicAdd(&qb[c0+4], qB.x); atomicAdd(&qb[c0+5], qB.y); atomicAdd(&qb[c0+6], qB.z); atomicAdd(&qb[c0+7], qB.w);
    __syncthreads();
    if (threadIdx.x < 128) {
        atomicAdd(&gsum[threadIdx.x], sb[threadIdx.x]);
        atomicAdd(&gss[threadIdx.x], qb[threadIdx.x]);
    }
}

// ---------------- GEMM2 (MFMA): h2 = bf16(elu(bn(g1))) @ bf16(W2) ----------------
__global__ __launch_bounds__(256) void k_gemm2(const uint4* __restrict__ g1,
                                               const float* __restrict__ W2,
                                               const float* __restrict__ gsum,
                                               const float* __restrict__ gss,
                                               const float* __restrict__ gamma,
                                               const float* __restrict__ beta,
                                               ushort* __restrict__ h2, int n) {
    __shared__ uint xsp[64 * LSTR];
    __shared__ uint wtp[64 * LSTR];
    __shared__ float sc[C_HID], sh[C_HID];
    const int tid = threadIdx.x;
    const int w = tid >> 6, l = tid & 63;
    const int lo = l & 15, hi = l >> 4;
    const int base = blockIdx.x * 64;

    if (tid < C_HID) {
        float inv_n = 1.f / (float)n;
        float mean = gsum[tid] * inv_n;
        float var = gss[tid] * inv_n - mean * mean;
        float s = gamma[tid] * rsqrtf(var + BN_EPS);
        sc[tid] = s;
        sh[tid] = beta[tid] - mean * s;
    }
    __syncthreads();

    for (int idx = tid; idx < 64 * 16; idx += 256) {
        int row = idx >> 4, q = idx & 15;
        int k8 = q * 8;
        uint4 u = make_uint4(0, 0, 0, 0);
        if (base + row < n) u = g1[(size_t)(base + row) * 16 + q];
        float t;
        float e0, e1, e2, e3, e4, e5, e6, e7;
        t = bl(u.x) * sc[k8+0] + sh[k8+0]; e0 = t > 0.f ? t : expm1f(t);
        t = bh(u.x) * sc[k8+1] + sh[k8+1]; e1 = t > 0.f ? t : expm1f(t);
        t = bl(u.y) * sc[k8+2] + sh[k8+2]; e2 = t > 0.f ? t : expm1f(t);
        t = bh(u.y) * sc[k8+3] + sh[k8+3]; e3 = t > 0.f ? t : expm1f(t);
        t = bl(u.z) * sc[k8+4] + sh[k8+4]; e4 = t > 0.f ? t : expm1f(t);
        t = bh(u.z) * sc[k8+5] + sh[k8+5]; e5 = t > 0.f ? t : expm1f(t);
        t = bl(u.w) * sc[k8+6] + sh[k8+6]; e6 = t > 0.f ? t : expm1f(t);
        t = bh(u.w) * sc[k8+7] + sh[k8+7]; e7 = t > 0.f ? t : expm1f(t);
        int wbase = row * LSTR + q * 4;
        xsp[wbase + 0] = pk(e0, e1);
        xsp[wbase + 1] = pk(e2, e3);
        xsp[wbase + 2] = pk(e4, e5);
        xsp[wbase + 3] = pk(e6, e7);
    }
    for (int idx = tid; idx < 64 * 16; idx += 256) {
        int kk = idx >> 4, n4 = (idx & 15) * 4;
        float4 w0 = *(const float4*)&W2[(size_t)(2 * kk) * C_OUT + n4];
        float4 w1 = *(const float4*)&W2[(size_t)(2 * kk + 1) * C_OUT + n4];
        wtp[(n4 + 0) * LSTR + kk] = pk(w0.x, w1.x);
        wtp[(n4 + 1) * LSTR + kk] = pk(w0.y, w1.y);
        wtp[(n4 + 2) * LSTR + kk] = pk(w0.z, w1.z);
        wtp[(n4 + 3) * LSTR + kk] = pk(w0.w, w1.w);
    }
    __syncthreads();

    fx4 acc[4];
    #pragma unroll
    for (int t = 0; t < 4; ++t) acc[t] = (fx4)(0.f);

    const int arow = (w * 16 + lo) * LSTR;
    #pragma unroll
    for (int kb = 0; kb < 4; ++kb) {
        const int ka = kb * 16 + hi * 4;
        uint4 ua;
        ua.x = xsp[arow + ka]; ua.y = xsp[arow + ka + 1];
        ua.z = xsp[arow + ka + 2]; ua.w = xsp[arow + ka + 3];
        bfx8 af = __builtin_bit_cast(bfx8, ua);
        #pragma unroll
        for (int nt = 0; nt < 4; ++nt) {
            const int brow = (nt * 16 + lo) * LSTR;
            uint4 ub;
            ub.x = wtp[brow + ka]; ub.y = wtp[brow + ka + 1];
            ub.z = wtp[brow + ka + 2]; ub.w = wtp[brow + ka + 3];
            bfx8 bf_ = __builtin_bit_cast(bfx8, ub);
            acc[nt] = __builtin_amdgcn_mfma_f32_16x16x32_bf16(af, bf_, acc[nt], 0, 0, 0);
        }
    }
    #pragma unroll
    for (int nt = 0; nt < 4; ++nt) {
        #pragma unroll
        for (int r = 0; r < 4; ++r) {
            int row = base + w * 16 + hi * 4 + r;
            if (row < n) h2[(size_t)row * C_OUT + nt * 16 + lo] = (ushort)bfr(acc[nt][r]);
        }
    }
}

// ---------------- gather2: bf16 rows, 1 node per 16 lanes, unroll 4 ----------------
__global__ __launch_bounds__(256) void k_gather2(const uint2* __restrict__ h,
                                                 const float* __restrict__ dinv,
                                                 const int* __restrict__ rowstart,
                                                 const int* __restrict__ csr,
                                                 const float* __restrict__ b,
                                                 float* __restrict__ out, int n) {
    int v = (blockIdx.x * 256 + threadIdx.x) >> 4;
    int l = threadIdx.x & 15;
    if (v >= n) return;
    float dv = dinv[v];
    int s0 = rowstart[v], s1 = rowstart[v + 1];
    float4 a;
    {
        uint2 u = h[(size_t)v * 16 + l];
        a.x = dv * bl(u.x); a.y = dv * bh(u.x); a.z = dv * bl(u.y); a.w = dv * bh(u.y);
    }
    int e = s0;
    for (; e + 3 < s1; e += 4) {
        int i0 = csr[e], i1 = csr[e + 1], i2 = csr[e + 2], i3 = csr[e + 3];
        float w0 = dinv[i0], w1 = dinv[i1], w2 = dinv[i2], w3 = dinv[i3];
        uint2 u0 = h[(size_t)i0 * 16 + l];
        uint2 u1 = h[(size_t)i1 * 16 + l];
        uint2 u2 = h[(size_t)i2 * 16 + l];
        uint2 u3 = h[(size_t)i3 * 16 + l];
        a.x += w0 * bl(u0.x) + w1 * bl(u1.x) + w2 * bl(u2.x) + w3 * bl(u3.x);
        a.y += w0 * bh(u0.x) + w1 * bh(u1.x) + w2 * bh(u2.x) + w3 * bh(u3.x);
        a.z += w0 * bl(u0.y) + w1 * bl(u1.y) + w2 * bl(u2.y) + w3 * bl(u3.y);
        a.w += w0 * bh(u0.y) + w1 * bh(u1.y) + w2 * bh(u2.y) + w3 * bh(u3.y);
    }
    for (; e < s1; ++e) {
        int s = csr[e];
        float w = dinv[s];
        uint2 u = h[(size_t)s * 16 + l];
        a.x += w * bl(u.x); a.y += w * bh(u.x); a.z += w * bl(u.y); a.w += w * bh(u.y);
    }
    float4 bb = *(const float4*)&b[l * 4];
    float4 o;
    o.x = a.x * dv + bb.x; o.y = a.y * dv + bb.y;
    o.z = a.z * dv + bb.z; o.w = a.w * dv + bb.w;
    *(float4*)&out[(size_t)v * C_OUT + l * 4] = o;
}

// ---------------- launch ----------------
extern "C" void kernel_launch(void* const* d_in, const int* in_sizes, int n_in,
                              void* d_out, int out_size, void* d_ws, size_t ws_size,
                              hipStream_t stream) {
    const float* x     = (const float*)d_in[0];
    const int*   ei    = (const int*)d_in[1];
    const float* W1    = (const float*)d_in[2];
    const float* b1    = (const float*)d_in[3];
    const float* gamma = (const float*)d_in[4];
    const float* beta  = (const float*)d_in[5];
    const float* W2    = (const float*)d_in[6];
    const float* b2    = (const float*)d_in[7];
    float* out = (float*)d_out;

    const int n = in_sizes[0] / C_IN;     // 50000
    const int E = in_sizes[1] / 2;        // 800000
    const int* src = ei;
    const int* dst = ei + E;

    char* p = (char*)d_ws;
    auto carve = [&](size_t bytes) {
        char* r = p;
        p += (bytes + 255) & ~(size_t)255;
        return r;
    };
    int*    deg      = (int*)   carve((size_t)n * 4);
    int*    rowstart = (int*)   carve((size_t)(n + 1) * 4);
    int*    cursor   = (int*)   carve((size_t)n * 4);
    int*    csr      = (int*)   carve((size_t)E * 4);
    float*  dinv     = (float*) carve((size_t)n * 4);
    ushort* h1       = (ushort*)carve((size_t)n * 128 * 2);
    ushort* g1       = (ushort*)carve((size_t)n * 128 * 2);
    ushort* h2       = (ushort*)carve((size_t)n * 64 * 2);
    float*  gsum     = (float*) carve(C_HID * 4);
    float*  gss      = (float*) carve(C_HID * 4);
    int*    part     = (int*)   carve(256 * 4);
    int*    bcur     = (int*)   carve(8 * 4);
    int2*   stage    = (int2*)  carve((size_t)8 * CAP * 8);

    const int nb = (n + 255) / 256;            // 196
    const int gblocks = (n * 16 + 255) / 256;  // 1 node per 16 lanes
    const int fc = (E + CHUNK - 1) / CHUNK;    // 782
    const float binv = 8.0f / (float)n;

    k_zero<<<(n + 264 + 255) / 256, 256, 0, stream>>>(deg, gsum, gss, bcur, n);
    k_bucket<<<fc, 256, 0, stream>>>(src, dst, deg, bcur, stage, E, binv);
    k_gemm1<<<(n + 63) / 64, 256, 0, stream>>>(x, W1, h1, n);
    k_part<<<nb, 256, 0, stream>>>(deg, part, n);
    k_apply<<<nb, 256, 0, stream>>>(deg, part, rowstart, cursor, dinv, n, nb);
    k_fill2<<<8 * NBB, 256, 0, stream>>>(stage, bcur, cursor, csr);
    k_gather1<<<gblocks, 256, 0, stream>>>((const uint4*)h1, dinv, rowstart, csr, b1, (uint4*)g1, n);
    k_bnstats<<<512, 256, 0, stream>>>((const uint4*)g1, gsum, gss, n);
    k_gemm2<<<(n + 63) / 64, 256, 0, stream>>>((const uint4*)g1, W2, gsum, gss, gamma, beta, h2, n);
    k_gather2<<<gblocks, 256, 0, stream>>>((const uint2*)h2, dinv, rowstart, csr, b2, out, n);
}